// Round 1
// baseline (257.119 us; speedup 1.0000x reference)
//
#include <hip/hip_runtime.h>
#include <hip/hip_bf16.h>

#define EMBED 128
#define HEADS 8
#define DH 16
#define FFN 512
#define BB 16
#define NN 256

// ---------------- Kernel A: LN1 + QKV projection (one block per row) -------
__global__ __launch_bounds__(128) void ln1_qkv_kernel(
    const float* __restrict__ x,
    const float* __restrict__ ln1_g, const float* __restrict__ ln1_b,
    const float* __restrict__ Wq, const float* __restrict__ bq,
    const float* __restrict__ Wk, const float* __restrict__ bk,
    const float* __restrict__ Wv, const float* __restrict__ bv,
    float* __restrict__ q, float* __restrict__ k, float* __restrict__ v)
{
    const int row = blockIdx.x;          // b*N + i
    const int e = threadIdx.x;           // 0..127
    __shared__ float red[128];
    __shared__ float xn[128];

    float xv = x[(size_t)row * EMBED + e];

    red[e] = xv;
    __syncthreads();
    for (int s = 64; s > 0; s >>= 1) { if (e < s) red[e] += red[e + s]; __syncthreads(); }
    float mu = red[0] * (1.0f / EMBED);
    __syncthreads();
    float d = xv - mu;
    red[e] = d * d;
    __syncthreads();
    for (int s = 64; s > 0; s >>= 1) { if (e < s) red[e] += red[e + s]; __syncthreads(); }
    float var = red[0] * (1.0f / EMBED);
    float rs = rsqrtf(var + 1e-5f);
    xn[e] = d * rs * ln1_g[e] + ln1_b[e];
    __syncthreads();

    float aq = bq[e], ak = bk[e], av = bv[e];
    #pragma unroll 8
    for (int c = 0; c < EMBED; ++c) {
        float xc = xn[c];
        aq += xc * Wq[c * EMBED + e];
        ak += xc * Wk[c * EMBED + e];
        av += xc * Wv[c * EMBED + e];
    }
    size_t o = (size_t)row * EMBED + e;
    q[o] = aq; k[o] = ak; v[o] = av;
}

// ---- Kernel B: scores(content+pos) + softmax + PV + Wo + LN2 + FFN --------
__global__ __launch_bounds__(256) void attn_ffn_kernel(
    const float* __restrict__ x,
    const float* __restrict__ pe,
    const float* __restrict__ mask,
    const float* __restrict__ q, const float* __restrict__ k, const float* __restrict__ v,
    const float* __restrict__ Wo, const float* __restrict__ bo,
    const float* __restrict__ ln2_g, const float* __restrict__ ln2_b,
    const float* __restrict__ W1, const float* __restrict__ b1,
    const float* __restrict__ W2, const float* __restrict__ b2,
    float* __restrict__ out)
{
    const int row = blockIdx.x;      // b*N + i
    const int bb  = row >> 8;        // N = 256
    const int t   = threadIdx.x;     // 0..255

    __shared__ float sc[HEADS][NN + 1];  // scores -> probs, padded stride 257
    __shared__ float qs[EMBED];
    __shared__ float pv[2][EMBED];
    __shared__ float ctx[EMBED];
    __shared__ float xn2[EMBED];
    __shared__ float hbuf[FFN];
    __shared__ float red[256];

    if (t < EMBED) qs[t] = q[(size_t)row * EMBED + t];
    __syncthreads();

    // ---- Phase 1: scores. group g (32 lanes) handles j = jt*8 + g --------
    const int g = t >> 5;            // 0..7
    const int l = t & 31;            // lane in group; covers dims 4l..4l+3
    float4 q4 = *reinterpret_cast<const float4*>(&qs[4 * l]);

    const size_t pe_row = (size_t)row * NN * EMBED;
    const size_t mrow   = (size_t)row * NN;
    for (int jt = 0; jt < 32; ++jt) {
        const int j = jt * 8 + g;
        const float4 p4 = *reinterpret_cast<const float4*>(pe + pe_row + (size_t)j * EMBED + 4 * l);
        const float4 k4 = *reinterpret_cast<const float4*>(k + (size_t)(bb * NN + j) * EMBED + 4 * l);
        float s = q4.x * (p4.x + k4.x) + q4.y * (p4.y + k4.y)
                + q4.z * (p4.z + k4.z) + q4.w * (p4.w + k4.w);
        // reduce the 4 lanes that make up one head (dh=16 = 4 lanes * 4 dims)
        s += __shfl_xor(s, 1);
        s += __shfl_xor(s, 2);
        if ((l & 3) == 0) {
            const int h = l >> 2;    // 0..7
            sc[h][j] = s * 0.25f + mask[mrow + j];   // 1/sqrt(16) = 0.25
        }
    }
    __syncthreads();

    // ---- Phase 2: softmax per head; group g handles head g ----------------
    {
        float vals[8];
        float m = -1e30f;
        #pragma unroll
        for (int r = 0; r < 8; ++r) { vals[r] = sc[g][l + 32 * r]; m = fmaxf(m, vals[r]); }
        #pragma unroll
        for (int off = 16; off >= 1; off >>= 1) m = fmaxf(m, __shfl_xor(m, off));
        float ssum = 0.f;
        #pragma unroll
        for (int r = 0; r < 8; ++r) { float e2 = __expf(vals[r] - m); vals[r] = e2; ssum += e2; }
        #pragma unroll
        for (int off = 16; off >= 1; off >>= 1) ssum += __shfl_xor(ssum, off);
        float inv = 1.0f / ssum;
        #pragma unroll
        for (int r = 0; r < 8; ++r) sc[g][l + 32 * r] = vals[r] * inv;
    }
    __syncthreads();

    // ---- Phase 3: ctx = attn @ v  (split j-range across two halves) ------
    {
        const int e    = t & 127;
        const int half = t >> 7;
        const int h    = e >> 4;
        float acc = 0.f;
        const float* vb = v + (size_t)(bb * NN + half * 128) * EMBED + e;
        const float* sr = &sc[h][half * 128];
        for (int j = 0; j < 128; ++j) acc += sr[j] * vb[(size_t)j * EMBED];
        pv[half][e] = acc;
    }
    __syncthreads();
    if (t < EMBED) ctx[t] = pv[0][t] + pv[1][t];
    __syncthreads();

    // ---- Phase 4: attn_out = ctx @ Wo + bo; residual ----------------------
    float x2v = 0.f;
    if (t < EMBED) {
        float acc = bo[t];
        #pragma unroll 8
        for (int c = 0; c < EMBED; ++c) acc += ctx[c] * Wo[c * EMBED + t];
        x2v = x[(size_t)row * EMBED + t] + acc;
    }
    __syncthreads();

    // ---- Phase 5: LN2 -----------------------------------------------------
    red[t] = (t < EMBED) ? x2v : 0.f;
    __syncthreads();
    for (int s = 128; s > 0; s >>= 1) { if (t < s) red[t] += red[t + s]; __syncthreads(); }
    float mu = red[0] * (1.0f / EMBED);
    __syncthreads();
    float dv = (t < EMBED) ? (x2v - mu) : 0.f;
    red[t] = dv * dv;
    __syncthreads();
    for (int s = 128; s > 0; s >>= 1) { if (t < s) red[t] += red[t + s]; __syncthreads(); }
    float var = red[0] * (1.0f / EMBED);
    float rs2 = rsqrtf(var + 1e-5f);
    if (t < EMBED) xn2[t] = dv * rs2 * ln2_g[t] + ln2_b[t];
    __syncthreads();

    // ---- Phase 6: FFN -----------------------------------------------------
    {
        float a0 = b1[t], a1 = b1[t + 256];
        #pragma unroll 8
        for (int c = 0; c < EMBED; ++c) {
            float xc = xn2[c];
            a0 += xc * W1[c * FFN + t];
            a1 += xc * W1[c * FFN + t + 256];
        }
        hbuf[t]       = fmaxf(a0, 0.f);
        hbuf[t + 256] = fmaxf(a1, 0.f);
    }
    __syncthreads();
    if (t < EMBED) {
        float acc = b2[t];
        #pragma unroll 8
        for (int f = 0; f < FFN; ++f) acc += hbuf[f] * W2[f * EMBED + t];
        out[(size_t)row * EMBED + t] = x2v + acc;
    }
}

extern "C" void kernel_launch(void* const* d_in, const int* in_sizes, int n_in,
                              void* d_out, int out_size, void* d_ws, size_t ws_size,
                              hipStream_t stream) {
    const float* x    = (const float*)d_in[0];
    const float* pe   = (const float*)d_in[1];
    const float* mask = (const float*)d_in[2];
    const float* ln1g = (const float*)d_in[3];
    const float* ln1b = (const float*)d_in[4];
    const float* Wq   = (const float*)d_in[5];
    const float* bq   = (const float*)d_in[6];
    const float* Wk   = (const float*)d_in[7];
    const float* bk   = (const float*)d_in[8];
    const float* Wv   = (const float*)d_in[9];
    const float* bv   = (const float*)d_in[10];
    const float* Wo   = (const float*)d_in[11];
    const float* bo   = (const float*)d_in[12];
    const float* ln2g = (const float*)d_in[13];
    const float* ln2b = (const float*)d_in[14];
    const float* W1   = (const float*)d_in[15];
    const float* b1   = (const float*)d_in[16];
    const float* W2   = (const float*)d_in[17];
    const float* b2   = (const float*)d_in[18];
    float* out = (float*)d_out;

    float* q  = (float*)d_ws;
    float* kk = q  + (size_t)BB * NN * EMBED;
    float* vv = kk + (size_t)BB * NN * EMBED;

    ln1_qkv_kernel<<<BB * NN, 128, 0, stream>>>(x, ln1g, ln1b, Wq, bq, Wk, bk, Wv, bv, q, kk, vv);
    attn_ffn_kernel<<<BB * NN, 256, 0, stream>>>(x, pe, mask, q, kk, vv, Wo, bo,
                                                 ln2g, ln2b, W1, b1, W2, b2, out);
}

// Round 2
// 252.201 us; speedup vs baseline: 1.0195x; 1.0195x over previous
//
#include <hip/hip_runtime.h>
#include <hip/hip_bf16.h>

#define EMBED 128
#define HEADS 8
#define DH 16
#define FFN 512
#define BB 16
#define NN 256

// ---------------- Kernel A: LN1 + QKV projection (one block per row) -------
__global__ __launch_bounds__(128) void ln1_qkv_kernel(
    const float* __restrict__ x,
    const float* __restrict__ ln1_g, const float* __restrict__ ln1_b,
    const float* __restrict__ Wq, const float* __restrict__ bq,
    const float* __restrict__ Wk, const float* __restrict__ bk,
    const float* __restrict__ Wv, const float* __restrict__ bv,
    float* __restrict__ q, float* __restrict__ k, float* __restrict__ v)
{
    const int row = blockIdx.x;          // b*N + i
    const int e = threadIdx.x;           // 0..127
    __shared__ float red[128];
    __shared__ float xn[128];

    float xv = x[(size_t)row * EMBED + e];

    red[e] = xv;
    __syncthreads();
    for (int s = 64; s > 0; s >>= 1) { if (e < s) red[e] += red[e + s]; __syncthreads(); }
    float mu = red[0] * (1.0f / EMBED);
    __syncthreads();
    float d = xv - mu;
    red[e] = d * d;
    __syncthreads();
    for (int s = 64; s > 0; s >>= 1) { if (e < s) red[e] += red[e + s]; __syncthreads(); }
    float var = red[0] * (1.0f / EMBED);
    float rs = rsqrtf(var + 1e-5f);
    xn[e] = d * rs * ln1_g[e] + ln1_b[e];
    __syncthreads();

    float aq = bq[e], ak = bk[e], av = bv[e];
    #pragma unroll 8
    for (int c = 0; c < EMBED; ++c) {
        float xc = xn[c];
        aq += xc * Wq[c * EMBED + e];
        ak += xc * Wk[c * EMBED + e];
        av += xc * Wv[c * EMBED + e];
    }
    size_t o = (size_t)row * EMBED + e;
    q[o] = aq; k[o] = ak; v[o] = av;
}

// ---- Kernel B: scores (content + pos) + softmax -> probs ------------------
// One block per (b,i) row. Dominated by the coalesced stream of pe[b,i,:,:].
__global__ __launch_bounds__(256) void scores_softmax_kernel(
    const float* __restrict__ pe,
    const float* __restrict__ mask,
    const float* __restrict__ q, const float* __restrict__ k,
    float* __restrict__ probs)
{
    const int row = blockIdx.x;      // b*N + i
    const int bb  = row >> 8;        // N = 256
    const int t   = threadIdx.x;     // 0..255

    __shared__ float sc[HEADS][NN + 1];
    __shared__ float qs[EMBED];

    if (t < EMBED) qs[t] = q[(size_t)row * EMBED + t];
    __syncthreads();

    const int g = t >> 5;            // 0..7 (group of 32 lanes)
    const int l = t & 31;            // lane covers dims 4l..4l+3
    float4 q4 = *reinterpret_cast<const float4*>(&qs[4 * l]);

    const size_t pe_row = (size_t)row * NN * EMBED;
    const size_t mrow   = (size_t)row * NN;
    #pragma unroll 4
    for (int jt = 0; jt < 32; ++jt) {
        const int j = jt * 8 + g;
        const float4 p4 = *reinterpret_cast<const float4*>(pe + pe_row + (size_t)j * EMBED + 4 * l);
        const float4 k4 = *reinterpret_cast<const float4*>(k + (size_t)(bb * NN + j) * EMBED + 4 * l);
        float s = q4.x * (p4.x + k4.x) + q4.y * (p4.y + k4.y)
                + q4.z * (p4.z + k4.z) + q4.w * (p4.w + k4.w);
        s += __shfl_xor(s, 1);
        s += __shfl_xor(s, 2);
        if ((l & 3) == 0) {
            sc[l >> 2][j] = s * 0.25f + mask[mrow + j];   // 1/sqrt(16)
        }
    }
    __syncthreads();

    // softmax per head; group g handles head g; write probs [row][h][j]
    {
        float vals[8];
        float m = -1e30f;
        #pragma unroll
        for (int r = 0; r < 8; ++r) { vals[r] = sc[g][l + 32 * r]; m = fmaxf(m, vals[r]); }
        #pragma unroll
        for (int off = 16; off >= 1; off >>= 1) m = fmaxf(m, __shfl_xor(m, off));
        float ssum = 0.f;
        #pragma unroll
        for (int r = 0; r < 8; ++r) { float e2 = __expf(vals[r] - m); vals[r] = e2; ssum += e2; }
        #pragma unroll
        for (int off = 16; off >= 1; off >>= 1) ssum += __shfl_xor(ssum, off);
        float inv = 1.0f / ssum;
        float* pout = probs + ((size_t)row * HEADS + g) * NN;
        #pragma unroll
        for (int r = 0; r < 8; ++r) pout[l + 32 * r] = vals[r] * inv;
    }
}

// ---- Kernel C: PV + Wo + residual + LN2 + FFN + residual ------------------
// One block per 4 rows of the same batch: weights/v read once, used 4x.
__global__ __launch_bounds__(256) void pv_ffn_kernel(
    const float* __restrict__ x,
    const float* __restrict__ probs,
    const float* __restrict__ v,
    const float* __restrict__ Wo, const float* __restrict__ bo,
    const float* __restrict__ ln2_g, const float* __restrict__ ln2_b,
    const float* __restrict__ W1, const float* __restrict__ b1,
    const float* __restrict__ W2, const float* __restrict__ b2,
    float* __restrict__ out)
{
    const int blk  = blockIdx.x;         // 0..1023
    const int b    = blk >> 6;           // 64 blocks per batch
    const int row0 = b * NN + ((blk & 63) << 2);   // first of 4 global rows
    const int t    = threadIdx.x;        // 0..255

    __shared__ float pr[4][HEADS][NN + 1];   // ~32.9 KB, padded for banks
    __shared__ float pvred[2][4][EMBED];
    __shared__ float ctx[4][EMBED];
    __shared__ float x2s[4][EMBED];
    __shared__ float xn2[4][EMBED];
    __shared__ float hb[4][FFN];
    __shared__ float mus[4], rss[4];

    // stage probs for 4 rows: 32 (r,h) segments of 256 floats, coalesced
    #pragma unroll
    for (int rh = 0; rh < 32; ++rh) {
        const int r = rh >> 3, h = rh & 7;
        pr[r][h][t] = probs[((size_t)(row0 + r) * HEADS + h) * NN + t];
    }
    __syncthreads();

    // ---- PV: ctx[r][e] = sum_j pr[r][h(e)][j] * v[b,j,e] ------------------
    {
        const int e = t & 127, half = t >> 7, h = e >> 4;
        float a0 = 0.f, a1 = 0.f, a2 = 0.f, a3 = 0.f;
        const float* vb = v + ((size_t)(b * NN + half * 128)) * EMBED + e;
        const float* p0 = &pr[0][h][half * 128];
        const float* p1 = &pr[1][h][half * 128];
        const float* p2 = &pr[2][h][half * 128];
        const float* p3 = &pr[3][h][half * 128];
        #pragma unroll 8
        for (int j = 0; j < 128; ++j) {
            const float vv = vb[(size_t)j * EMBED];
            a0 += p0[j] * vv; a1 += p1[j] * vv; a2 += p2[j] * vv; a3 += p3[j] * vv;
        }
        pvred[half][0][e] = a0; pvred[half][1][e] = a1;
        pvred[half][2][e] = a2; pvred[half][3][e] = a3;
    }
    __syncthreads();
    if (t < 128) {
        #pragma unroll
        for (int r = 0; r < 4; ++r) ctx[r][t] = pvred[0][r][t] + pvred[1][r][t];
    }
    __syncthreads();

    // ---- Wo + residual: thread (e, rp) handles rows {2rp, 2rp+1} ----------
    {
        const int e = t & 127, rp = t >> 7;
        float a0 = bo[e], a1 = bo[e];
        #pragma unroll 8
        for (int c = 0; c < EMBED; ++c) {
            const float w = Wo[c * EMBED + e];
            a0 += ctx[2 * rp][c] * w;
            a1 += ctx[2 * rp + 1][c] * w;
        }
        a0 += x[(size_t)(row0 + 2 * rp) * EMBED + e];
        a1 += x[(size_t)(row0 + 2 * rp + 1) * EMBED + e];
        x2s[2 * rp][e] = a0;
        x2s[2 * rp + 1][e] = a1;
    }
    __syncthreads();

    // ---- LN2 stats: wave w (0..3) reduces row w via shuffles --------------
    {
        const int wid = t >> 6, l64 = t & 63;
        if (wid < 4) {
            const float v0 = x2s[wid][l64], v1 = x2s[wid][l64 + 64];
            float s = v0 + v1;
            float sq = v0 * v0 + v1 * v1;
            #pragma unroll
            for (int off = 32; off >= 1; off >>= 1) {
                s  += __shfl_xor(s, off);
                sq += __shfl_xor(sq, off);
            }
            if (l64 == 0) {
                const float mu = s * (1.0f / EMBED);
                const float var = sq * (1.0f / EMBED) - mu * mu;
                mus[wid] = mu;
                rss[wid] = rsqrtf(var + 1e-5f);
            }
        }
    }
    __syncthreads();
    {
        #pragma unroll
        for (int rr = 0; rr < 2; ++rr) {
            const int flat = t + 256 * rr;       // 0..511 = r*128+e
            const int r = flat >> 7, e = flat & 127;
            xn2[r][e] = (x2s[r][e] - mus[r]) * rss[r] * ln2_g[e] + ln2_b[e];
        }
    }
    __syncthreads();

    // ---- FFN layer 1: thread t covers hidden cols {t, t+256}, 4 rows ------
    {
        float h0[4], h1[4];
        #pragma unroll
        for (int r = 0; r < 4; ++r) { h0[r] = b1[t]; h1[r] = b1[t + 256]; }
        #pragma unroll 4
        for (int c = 0; c < EMBED; ++c) {
            const float w0 = W1[c * FFN + t];
            const float w1 = W1[c * FFN + t + 256];
            #pragma unroll
            for (int r = 0; r < 4; ++r) {
                const float xc = xn2[r][c];
                h0[r] += xc * w0;
                h1[r] += xc * w1;
            }
        }
        #pragma unroll
        for (int r = 0; r < 4; ++r) {
            hb[r][t]       = fmaxf(h0[r], 0.f);
            hb[r][t + 256] = fmaxf(h1[r], 0.f);
        }
    }
    __syncthreads();

    // ---- FFN layer 2 + residual: thread (e, rp) rows {2rp, 2rp+1} ---------
    {
        const int e = t & 127, rp = t >> 7;
        const int ra = 2 * rp, rb = 2 * rp + 1;
        float a0 = b2[e], a1 = b2[e];
        #pragma unroll 8
        for (int f = 0; f < FFN; ++f) {
            const float w = W2[f * EMBED + e];
            a0 += hb[ra][f] * w;
            a1 += hb[rb][f] * w;
        }
        out[(size_t)(row0 + ra) * EMBED + e] = x2s[ra][e] + a0;
        out[(size_t)(row0 + rb) * EMBED + e] = x2s[rb][e] + a1;
    }
}

extern "C" void kernel_launch(void* const* d_in, const int* in_sizes, int n_in,
                              void* d_out, int out_size, void* d_ws, size_t ws_size,
                              hipStream_t stream) {
    const float* x    = (const float*)d_in[0];
    const float* pe   = (const float*)d_in[1];
    const float* mask = (const float*)d_in[2];
    const float* ln1g = (const float*)d_in[3];
    const float* ln1b = (const float*)d_in[4];
    const float* Wq   = (const float*)d_in[5];
    const float* bq   = (const float*)d_in[6];
    const float* Wk   = (const float*)d_in[7];
    const float* bk   = (const float*)d_in[8];
    const float* Wv   = (const float*)d_in[9];
    const float* bv   = (const float*)d_in[10];
    const float* Wo   = (const float*)d_in[11];
    const float* bo   = (const float*)d_in[12];
    const float* ln2g = (const float*)d_in[13];
    const float* ln2b = (const float*)d_in[14];
    const float* W1   = (const float*)d_in[15];
    const float* b1   = (const float*)d_in[16];
    const float* W2   = (const float*)d_in[17];
    const float* b2   = (const float*)d_in[18];
    float* out = (float*)d_out;

    float* q     = (float*)d_ws;
    float* kk    = q  + (size_t)BB * NN * EMBED;
    float* vv    = kk + (size_t)BB * NN * EMBED;
    float* probs = vv + (size_t)BB * NN * EMBED;   // B*N*H*N floats = 33.5 MB

    ln1_qkv_kernel<<<BB * NN, 128, 0, stream>>>(x, ln1g, ln1b, Wq, bq, Wk, bk, Wv, bv, q, kk, vv);
    scores_softmax_kernel<<<BB * NN, 256, 0, stream>>>(pe, mask, q, kk, probs);
    pv_ffn_kernel<<<BB * NN / 4, 256, 0, stream>>>(x, probs, vv, Wo, bo,
                                                   ln2g, ln2b, W1, b1, W2, b2, out);
}